// Round 1
// baseline (2052.213 us; speedup 1.0000x reference)
//
#include <hip/hip_runtime.h>

constexpr int kNL = 16384, kND = 4096, kNM = 2048;
constexpr int kE = 262144;              // 2^18
constexpr int kFEAT = 256, kHID = 64, kOUTF = 128;
constexpr int kITEMS = 4096, kSIZE = 2048;

struct EdgePtrs { const int* p[12]; };

// ---- degree counting ------------------------------------------------------
__global__ void count_deg_kernel(EdgePtrs ep, float* __restrict__ deg) {
  unsigned idx = blockIdx.x * 256u + threadIdx.x;   // grid sized exactly 12*kE
  int k = idx >> 18;            // which of the 12 index arrays
  int e = idx & (kE - 1);
  atomicAdd(&deg[k * kNL + ep.p[k][e]], 1.0f);
}

__global__ void finalize_deg_kernel(float* __restrict__ deg) {
  int idx = blockIdx.x * 256 + threadIdx.x;         // grid = 12*kNL/256
  deg[idx] = 1.0f / sqrtf(fmaxf(deg[idx], 1.0f));
}

// ---- init accumulator rows with bias sum ----------------------------------
__global__ void init_acc_kernel(float* __restrict__ acc,
                                const float* __restrict__ b0,
                                const float* __restrict__ b1,
                                int total, int gmask) {
  int idx = blockIdx.x * 256 + threadIdx.x;
  if (idx >= total) return;
  int g = idx & gmask;
  acc[idx] = b0[g] + b1[g];
}

// ---- generic fp32 GEMM: C = act( [C +] (A .* rowScale) @ B + bias ) -------
// A: M x K row-major, B: K x N row-major.  M%64==0, N%64==0, K%16==0.
__global__ __launch_bounds__(256) void gemm_kernel(
    const float* __restrict__ A, const float* __restrict__ B,
    float* __restrict__ C, int M, int N, int K,
    const float* __restrict__ rowScale, const float* __restrict__ bias,
    int accumulate, int act) {
  __shared__ float As[16][65];
  __shared__ float Bs[16][64];
  int tid = threadIdx.x;
  int tx = tid & 15, ty = tid >> 4;
  int brow = blockIdx.y * 64, bcol = blockIdx.x * 64;

  // staging roles
  int ar = tid >> 2;             // 0..63 : A row within tile
  int ak = (tid & 3) * 4;        // 0,4,8,12
  float ascale = rowScale ? rowScale[brow + ar] : 1.0f;
  int bk = tid >> 4;             // 0..15
  int bc = (tid & 15) * 4;       // 0..60

  float c[4][4] = {};
  for (int k0 = 0; k0 < K; k0 += 16) {
    float4 va = *(const float4*)(A + (size_t)(brow + ar) * K + k0 + ak);
    As[ak + 0][ar] = va.x * ascale;
    As[ak + 1][ar] = va.y * ascale;
    As[ak + 2][ar] = va.z * ascale;
    As[ak + 3][ar] = va.w * ascale;
    float4 vb = *(const float4*)(B + (size_t)(k0 + bk) * N + bcol + bc);
    Bs[bk][bc + 0] = vb.x; Bs[bk][bc + 1] = vb.y;
    Bs[bk][bc + 2] = vb.z; Bs[bk][bc + 3] = vb.w;
    __syncthreads();
#pragma unroll
    for (int kk = 0; kk < 16; ++kk) {
      float a0 = As[kk][ty], a1 = As[kk][16 + ty];
      float a2 = As[kk][32 + ty], a3 = As[kk][48 + ty];
      float b0 = Bs[kk][tx], b1 = Bs[kk][16 + tx];
      float b2 = Bs[kk][32 + tx], b3 = Bs[kk][48 + tx];
      c[0][0] += a0 * b0; c[0][1] += a0 * b1; c[0][2] += a0 * b2; c[0][3] += a0 * b3;
      c[1][0] += a1 * b0; c[1][1] += a1 * b1; c[1][2] += a1 * b2; c[1][3] += a1 * b3;
      c[2][0] += a2 * b0; c[2][1] += a2 * b1; c[2][2] += a2 * b2; c[2][3] += a2 * b3;
      c[3][0] += a3 * b0; c[3][1] += a3 * b1; c[3][2] += a3 * b2; c[3][3] += a3 * b3;
    }
    __syncthreads();
  }
#pragma unroll
  for (int i = 0; i < 4; ++i) {
#pragma unroll
    for (int j = 0; j < 4; ++j) {
      int row = brow + i * 16 + ty;
      int col = bcol + j * 16 + tx;
      float v = c[i][j];
      if (accumulate) v += C[(size_t)row * N + col];
      if (bias) v += bias[col];
      if (act == 1) v = fmaxf(v, 0.0f);
      else if (act == 2) v = 1.0f / (1.0f + expf(-v));
      C[(size_t)row * N + col] = v;
    }
  }
}

// ---- edge scatter: acc[dst] += z[src] * sIn[dst] --------------------------
__global__ void scatter_kernel(const float* __restrict__ z,
                               const int* __restrict__ src,
                               const int* __restrict__ dst,
                               const float* __restrict__ sIn,
                               float* __restrict__ acc,
                               int gshift, int dstLimit) {
  unsigned idx = blockIdx.x * 256u + threadIdx.x;   // grid sized exactly kE<<gshift
  int e = idx >> gshift;
  int g = idx & ((1 << gshift) - 1);
  int d = dst[e];
  if (d >= dstLimit) return;
  int s = src[e];
  atomicAdd(&acc[((size_t)d << gshift) + g], z[((size_t)s << gshift) + g] * sIn[d]);
}

// ---- L1 row-normalize first 2048 rows -> emb ------------------------------
__global__ void l1norm_kernel(const float* __restrict__ h, float* __restrict__ emb) {
  int r = blockIdx.x;
  int t = threadIdx.x;  // 0..63
  float v0 = h[r * kOUTF + t];
  float v1 = h[r * kOUTF + 64 + t];
  float a = fabsf(v0) + fabsf(v1);
#pragma unroll
  for (int off = 32; off > 0; off >>= 1) a += __shfl_xor(a, off);
  float l1 = fmaxf(a, 1e-12f);
  emb[r * kOUTF + t] = v0 / l1;
  emb[r * kOUTF + 64 + t] = v1 / l1;
}

extern "C" void kernel_launch(void* const* d_in, const int* in_sizes, int n_in,
                              void* d_out, int out_size, void* d_ws, size_t ws_size,
                              hipStream_t stream) {
  const float* h_L = (const float*)d_in[0];
  const float* h_D = (const float*)d_in[1];
  const float* h_M = (const float*)d_in[2];
  const float* Adj = (const float*)d_in[3];
  EdgePtrs ep;
  for (int i = 0; i < 12; ++i) ep.p[i] = (const int*)d_in[4 + i];
  const float* W[3]  = {(const float*)d_in[16], (const float*)d_in[18], (const float*)d_in[20]};
  const float* Bb[3] = {(const float*)d_in[17], (const float*)d_in[19], (const float*)d_in[21]};
  const float* f1_w = (const float*)d_in[22];
  const float* f1_b = (const float*)d_in[23];
  const float* f2_w = (const float*)d_in[24];
  const float* f2_b = (const float*)d_in[25];
  const float* f3_w = (const float*)d_in[26];
  const float* f3_b = (const float*)d_in[27];
  const float* f4_w = (const float*)d_in[28];
  const float* f4_b = (const float*)d_in[29];

  // workspace layout (floats)
  float* ws = (float*)d_ws;
  size_t off = 0;
  float* deg = ws + off;   off += (size_t)12 * kNL;          // 12 arrays of 16384
  float* bufL0 = ws + off; off += (size_t)kNL * kHID;
  float* bufD0 = ws + off; off += (size_t)kND * kHID;
  float* bufM0 = ws + off; off += (size_t)kNM * kHID;
  float* bufL1 = ws + off; off += (size_t)kNL * kHID;
  float* bufD1 = ws + off; off += (size_t)kND * kHID;
  float* bufM1 = ws + off; off += (size_t)kNM * kHID;
  float* accL3 = ws + off; off += (size_t)kSIZE * kOUTF;
  float* z     = ws + off; off += (size_t)kNL * kOUTF;       // max z tile
  float* x1    = ws + off; off += (size_t)kSIZE * 256;
  float* x2    = ws + off; off += (size_t)kSIZE * 512;
  float* x3    = ws + off; off += (size_t)kSIZE * 1024;

  // 1) degrees
  hipMemsetAsync(deg, 0, (size_t)12 * kNL * sizeof(float), stream);
  count_deg_kernel<<<12 * kE / 256, 256, 0, stream>>>(ep, deg);
  finalize_deg_kernel<<<12 * kNL / 256, 256, 0, stream>>>(deg);

  const int srcT[6] = {0, 1, 0, 2, 1, 2};
  const int dstT[6] = {1, 0, 2, 0, 2, 1};
  const int nsrc[6] = {kNL, kND, kNL, kNM, kND, kNM};
  const int ndst[6] = {kND, kNL, kNM, kNL, kNM, kND};

  const float* cur[3] = {h_L, h_D, h_M};
  float* bufs[2][3] = {{bufL0, bufD0, bufM0}, {bufL1, bufD1, bufM1}};
  int nnode[3] = {kNL, kND, kNM};
  int F = kFEAT;

  // 2) hetero layers 1 & 2 (output width 64)
  for (int layer = 0; layer < 2; ++layer) {
    int G = kHID, gshift = 6;
    float** nxt = bufs[layer];
    const float* Wl = W[layer];
    const float* bl = Bb[layer];
    init_acc_kernel<<<(kNL * G + 255) / 256, 256, 0, stream>>>(nxt[0], bl + 1 * G, bl + 3 * G, kNL * G, G - 1);
    init_acc_kernel<<<(kND * G + 255) / 256, 256, 0, stream>>>(nxt[1], bl + 0 * G, bl + 5 * G, kND * G, G - 1);
    init_acc_kernel<<<(kNM * G + 255) / 256, 256, 0, stream>>>(nxt[2], bl + 2 * G, bl + 4 * G, kNM * G, G - 1);
    for (int t = 0; t < 6; ++t) {
      gemm_kernel<<<dim3(G / 64, nsrc[t] / 64), 256, 0, stream>>>(
          cur[srcT[t]], Wl + (size_t)t * F * G, z, nsrc[t], G, F,
          deg + (size_t)(2 * t) * kNL, nullptr, 0, 0);
      scatter_kernel<<<(kE << gshift) / 256, 256, 0, stream>>>(
          z, ep.p[2 * t], ep.p[2 * t + 1], deg + (size_t)(2 * t + 1) * kNL,
          nxt[dstT[t]], gshift, ndst[t]);
    }
    cur[0] = nxt[0]; cur[1] = nxt[1]; cur[2] = nxt[2];
    F = G;
  }

  // 3) layer 3: only oL, only rows [0, 2048)
  {
    int G = kOUTF, gshift = 7;
    const float* Wl = W[2];
    const float* bl = Bb[2];
    init_acc_kernel<<<(kSIZE * G + 255) / 256, 256, 0, stream>>>(accL3, bl + 1 * G, bl + 3 * G, kSIZE * G, G - 1);
    const int types[2] = {1, 3};  // DL, ML
    for (int ti = 0; ti < 2; ++ti) {
      int t = types[ti];
      gemm_kernel<<<dim3(G / 64, nsrc[t] / 64), 256, 0, stream>>>(
          cur[srcT[t]], Wl + (size_t)t * F * G, z, nsrc[t], G, F,
          deg + (size_t)(2 * t) * kNL, nullptr, 0, 0);
      scatter_kernel<<<(kE << gshift) / 256, 256, 0, stream>>>(
          z, ep.p[2 * t], ep.p[2 * t + 1], deg + (size_t)(2 * t + 1) * kNL,
          accL3, gshift, kSIZE);
    }
  }

  // 4) L1 normalize -> fake_embedding (output 0)
  float* emb  = (float*)d_out;
  float* outx = (float*)d_out + (size_t)kSIZE * kOUTF;
  l1norm_kernel<<<kSIZE, 64, 0, stream>>>(accL3, emb);

  // 5) MLP
  // x1 = relu(Adj @ f1_w[:4096] + emb @ f1_w[4096:] + f1_b)
  gemm_kernel<<<dim3(256 / 64, kSIZE / 64), 256, 0, stream>>>(
      Adj, f1_w, x1, kSIZE, 256, kITEMS, nullptr, nullptr, 0, 0);
  gemm_kernel<<<dim3(256 / 64, kSIZE / 64), 256, 0, stream>>>(
      emb, f1_w + (size_t)kITEMS * 256, x1, kSIZE, 256, kOUTF, nullptr, f1_b, 1, 1);
  gemm_kernel<<<dim3(512 / 64, kSIZE / 64), 256, 0, stream>>>(
      x1, f2_w, x2, kSIZE, 512, 256, nullptr, f2_b, 0, 1);
  gemm_kernel<<<dim3(1024 / 64, kSIZE / 64), 256, 0, stream>>>(
      x2, f3_w, x3, kSIZE, 1024, 512, nullptr, f3_b, 0, 1);
  gemm_kernel<<<dim3(4096 / 64, kSIZE / 64), 256, 0, stream>>>(
      x3, f4_w, outx, kSIZE, 4096, 1024, nullptr, f4_b, 0, 2);
}

// Round 2
// 1418.656 us; speedup vs baseline: 1.4466x; 1.4466x over previous
//
#include <hip/hip_runtime.h>

constexpr int kNL = 16384, kND = 4096, kNM = 2048;
constexpr int kE = 262144;              // 2^18
constexpr int kFEAT = 256, kHID = 64, kOUTF = 128;
constexpr int kITEMS = 4096, kSIZE = 2048;

typedef unsigned short ushort_t;
typedef __attribute__((ext_vector_type(8))) short short8v;
typedef __attribute__((ext_vector_type(4))) float f32x4;

struct EdgePtrs { const int* p[12]; };

__device__ inline ushort_t f2bf(float f) {
  unsigned u = __builtin_bit_cast(unsigned, f);
  unsigned r = u + 0x7fffu + ((u >> 16) & 1u);
  return (ushort_t)(r >> 16);
}
__device__ inline float bf2f(ushort_t b) {
  unsigned u = ((unsigned)b) << 16;
  return __builtin_bit_cast(float, u);
}

// ---- degree counting ------------------------------------------------------
__global__ void count_deg_kernel(EdgePtrs ep, float* __restrict__ deg) {
  unsigned idx = blockIdx.x * 256u + threadIdx.x;   // grid sized exactly 12*kE
  int k = idx >> 18;
  int e = idx & (kE - 1);
  atomicAdd(&deg[k * kNL + ep.p[k][e]], 1.0f);
}

__global__ void finalize_deg_kernel(float* __restrict__ deg) {
  int idx = blockIdx.x * 256 + threadIdx.x;         // grid = 12*kNL/256
  deg[idx] = 1.0f / sqrtf(fmaxf(deg[idx], 1.0f));
}

// ---- init accumulator rows with bias sum ----------------------------------
__global__ void init_acc_kernel(float* __restrict__ acc,
                                const float* __restrict__ b0,
                                const float* __restrict__ b1,
                                int total, int gmask) {
  int idx = blockIdx.x * 256 + threadIdx.x;
  if (idx >= total) return;
  int g = idx & gmask;
  acc[idx] = b0[g] + b1[g];
}

// ---- fp32 -> bf16 elementwise (n multiple of 4) ---------------------------
__global__ void cvt_bf16_kernel(const float* __restrict__ in,
                                ushort_t* __restrict__ out, int n4) {
  int idx = blockIdx.x * 256 + threadIdx.x;
  if (idx >= n4) return;
  float4 v = ((const float4*)in)[idx];
  ushort_t* o = out + (size_t)idx * 4;
  o[0] = f2bf(v.x); o[1] = f2bf(v.y); o[2] = f2bf(v.z); o[3] = f2bf(v.w);
}

// ---- transpose + convert: in [K][N] f32 -> out [N][K] bf16 ----------------
// grid (N/32, K/32), block 256 (32x8)
__global__ void transpose_bf16_kernel(const float* __restrict__ in,
                                      ushort_t* __restrict__ out, int K, int N) {
  __shared__ float t[32][33];
  int n0 = blockIdx.x * 32, k0 = blockIdx.y * 32;
  int tx = threadIdx.x & 31, ty = threadIdx.x >> 5;
#pragma unroll
  for (int i = 0; i < 32; i += 8)
    t[ty + i][tx] = in[(size_t)(k0 + ty + i) * N + n0 + tx];
  __syncthreads();
#pragma unroll
  for (int i = 0; i < 32; i += 8)
    out[(size_t)(n0 + ty + i) * K + k0 + tx] = f2bf(t[tx][ty + i]);
}

// ---- bf16 MFMA GEMM: out = act( [Cin +] A @ Bt^T + bias ) -----------------
// A: M x K bf16 row-major (lda=K). Bt: N x K bf16 row-major (row stride ldb).
// M%128==0, N%64==0, K%32==0. Cin fp32 or null. out fp32 or bf16.
__global__ __launch_bounds__(256) void gemm_bf16_kernel(
    const ushort_t* __restrict__ A, const ushort_t* __restrict__ Bt,
    const float* __restrict__ Cin, void* __restrict__ out, int outBf16,
    int M, int N, int K, int ldb,
    const float* __restrict__ bias, int act) {
  __shared__ ushort_t As[128 * 32];   // 8 KB, rows of 32 bf16, 16B-slot XOR swizzle
  __shared__ ushort_t Bs[64 * 32];    // 4 KB
  int tid = threadIdx.x;
  int wave = tid >> 6, lane = tid & 63;
  int brow = blockIdx.y * 128, bcol = blockIdx.x * 64;

  // staging: thread covers A bytes [tid*16, +16) and [4096 + tid*16, +16), B [tid*16)
  int ar0 = tid >> 2;            // 0..63
  int as0 = tid & 3;             // 16B slot within 64B row
  int ar1 = 64 + ar0;
  const ushort_t* gA0 = A + (size_t)(brow + ar0) * K + as0 * 8;
  const ushort_t* gA1 = A + (size_t)(brow + ar1) * K + as0 * 8;
  const ushort_t* gB  = Bt + (size_t)(bcol + ar0) * ldb + as0 * 8;
  int wA0 = ar0 * 32 + ((as0 ^ ((ar0 >> 1) & 3)) * 8);
  int wA1 = ar1 * 32 + ((as0 ^ ((ar1 >> 1) & 3)) * 8);
  int wB  = ar0 * 32 + ((as0 ^ ((ar0 >> 1) & 3)) * 8);

  int fr = lane & 15, fq = lane >> 4;

  f32x4 acc[2][4] = {};
  short8v ra0 = *(const short8v*)gA0;
  short8v ra1 = *(const short8v*)gA1;
  short8v rb  = *(const short8v*)gB;

  for (int k0 = 0; k0 < K; k0 += 32) {
    __syncthreads();
    *(short8v*)(As + wA0) = ra0;
    *(short8v*)(As + wA1) = ra1;
    *(short8v*)(Bs + wB)  = rb;
    __syncthreads();
    if (k0 + 32 < K) {
      ra0 = *(const short8v*)(gA0 + k0 + 32);
      ra1 = *(const short8v*)(gA1 + k0 + 32);
      rb  = *(const short8v*)(gB + k0 + 32);
    }
    short8v af[2], bf[4];
#pragma unroll
    for (int mi = 0; mi < 2; ++mi) {
      int row = wave * 32 + mi * 16 + fr;
      af[mi] = *(const short8v*)(As + row * 32 + ((fq ^ ((row >> 1) & 3)) * 8));
    }
#pragma unroll
    for (int ni = 0; ni < 4; ++ni) {
      int row = ni * 16 + fr;
      bf[ni] = *(const short8v*)(Bs + row * 32 + ((fq ^ ((row >> 1) & 3)) * 8));
    }
#pragma unroll
    for (int mi = 0; mi < 2; ++mi)
#pragma unroll
      for (int ni = 0; ni < 4; ++ni)
        acc[mi][ni] = __builtin_amdgcn_mfma_f32_16x16x32_bf16(af[mi], bf[ni], acc[mi][ni], 0, 0, 0);
  }

#pragma unroll
  for (int mi = 0; mi < 2; ++mi)
#pragma unroll
    for (int ni = 0; ni < 4; ++ni)
#pragma unroll
      for (int r = 0; r < 4; ++r) {
        int row = brow + wave * 32 + mi * 16 + fq * 4 + r;
        int col = bcol + ni * 16 + fr;
        float v = acc[mi][ni][r];
        if (Cin) v += Cin[(size_t)row * N + col];
        if (bias) v += bias[col];
        if (act == 1) v = fmaxf(v, 0.0f);
        else if (act == 2) v = 1.0f / (1.0f + expf(-v));
        if (outBf16) ((ushort_t*)out)[(size_t)row * N + col] = f2bf(v);
        else ((float*)out)[(size_t)row * N + col] = v;
      }
}

// ---- edge scatter: acc[dst] += z[src] * sOut[src] * sIn[dst] --------------
__global__ void scatter_kernel(const ushort_t* __restrict__ z,
                               const int* __restrict__ src,
                               const int* __restrict__ dst,
                               const float* __restrict__ sOut,
                               const float* __restrict__ sIn,
                               float* __restrict__ acc,
                               int gshift, int dstLimit) {
  unsigned idx = blockIdx.x * 256u + threadIdx.x;   // grid sized exactly kE<<gshift
  int e = idx >> gshift;
  int g = idx & ((1 << gshift) - 1);
  int d = dst[e];
  if (d >= dstLimit) return;
  int s = src[e];
  float zv = bf2f(z[((size_t)s << gshift) + g]);
  atomicAdd(&acc[((size_t)d << gshift) + g], zv * sOut[s] * sIn[d]);
}

// ---- L1 row-normalize first 2048 rows -> emb (fp32 + bf16) ----------------
__global__ void l1norm_kernel(const float* __restrict__ h, float* __restrict__ emb,
                              ushort_t* __restrict__ embb) {
  int r = blockIdx.x;
  int t = threadIdx.x;  // 0..63
  float v0 = h[r * kOUTF + t];
  float v1 = h[r * kOUTF + 64 + t];
  float a = fabsf(v0) + fabsf(v1);
#pragma unroll
  for (int off = 32; off > 0; off >>= 1) a += __shfl_xor(a, off);
  float l1 = fmaxf(a, 1e-12f);
  float e0 = v0 / l1, e1 = v1 / l1;
  emb[r * kOUTF + t] = e0;
  emb[r * kOUTF + 64 + t] = e1;
  embb[r * kOUTF + t] = f2bf(e0);
  embb[r * kOUTF + 64 + t] = f2bf(e1);
}

extern "C" void kernel_launch(void* const* d_in, const int* in_sizes, int n_in,
                              void* d_out, int out_size, void* d_ws, size_t ws_size,
                              hipStream_t stream) {
  const float* h_L = (const float*)d_in[0];
  const float* h_D = (const float*)d_in[1];
  const float* h_M = (const float*)d_in[2];
  const float* Adj = (const float*)d_in[3];
  EdgePtrs ep;
  for (int i = 0; i < 12; ++i) ep.p[i] = (const int*)d_in[4 + i];
  const float* W[3]  = {(const float*)d_in[16], (const float*)d_in[18], (const float*)d_in[20]};
  const float* Bb[3] = {(const float*)d_in[17], (const float*)d_in[19], (const float*)d_in[21]};
  const float* f1_w = (const float*)d_in[22];
  const float* f1_b = (const float*)d_in[23];
  const float* f2_w = (const float*)d_in[24];
  const float* f2_b = (const float*)d_in[25];
  const float* f3_w = (const float*)d_in[26];
  const float* f3_b = (const float*)d_in[27];
  const float* f4_w = (const float*)d_in[28];
  const float* f4_b = (const float*)d_in[29];

  // ---- workspace layout (float units; everything 16B aligned) ----
  float* ws = (float*)d_ws;
  size_t off = 0;
  auto allocF = [&](size_t n) { float* p = ws + off; off += (n + 3) & ~(size_t)3; return p; };
  auto allocB = [&](size_t n) { return (ushort_t*)allocF((n + 1) / 2); };  // n bf16 elems

  float* deg   = allocF((size_t)12 * kNL);
  float* bufL0 = allocF((size_t)kNL * kHID);
  float* bufD0 = allocF((size_t)kND * kHID);
  float* bufM0 = allocF((size_t)kNM * kHID);
  float* bufL1 = allocF((size_t)kNL * kHID);
  float* bufD1 = allocF((size_t)kND * kHID);
  float* bufM1 = allocF((size_t)kNM * kHID);
  float* accL3 = allocF((size_t)kSIZE * kOUTF);
  float* x1f   = allocF((size_t)kSIZE * 256);
  ushort_t* zb   = allocB((size_t)kNL * kHID);       // biggest z: 16384 x 64
  ushort_t* hLb  = allocB((size_t)kNL * kFEAT);
  ushort_t* hDb  = allocB((size_t)kND * kFEAT);
  ushort_t* hMb  = allocB((size_t)kNM * kFEAT);
  ushort_t* Adjb = allocB((size_t)kSIZE * kITEMS);
  ushort_t* aLb  = allocB((size_t)kNL * kHID);
  ushort_t* aDb  = allocB((size_t)kND * kHID);
  ushort_t* aMb  = allocB((size_t)kNM * kHID);
  ushort_t* W1t  = allocB((size_t)6 * kFEAT * kHID);
  ushort_t* W2t  = allocB((size_t)6 * kHID * kHID);
  ushort_t* W3t  = allocB((size_t)6 * kHID * kOUTF);
  ushort_t* f1t  = allocB((size_t)(kITEMS + kOUTF) * 256);
  ushort_t* f2t  = allocB((size_t)256 * 512);
  ushort_t* f3t  = allocB((size_t)512 * 1024);
  ushort_t* f4t  = allocB((size_t)1024 * kITEMS);
  ushort_t* embb = allocB((size_t)kSIZE * kOUTF);
  ushort_t* x1b  = allocB((size_t)kSIZE * 256);
  ushort_t* x2b  = allocB((size_t)kSIZE * 512);
  ushort_t* x3b  = allocB((size_t)kSIZE * 1024);

  auto cvt = [&](const float* in, ushort_t* out, size_t n) {
    int n4 = (int)(n / 4);
    cvt_bf16_kernel<<<(n4 + 255) / 256, 256, 0, stream>>>(in, out, n4);
  };
  auto tconv = [&](const float* in, ushort_t* out, int K, int N) {
    transpose_bf16_kernel<<<dim3(N / 32, K / 32), 256, 0, stream>>>(in, out, K, N);
  };
  auto gemm = [&](const ushort_t* A, const ushort_t* Bt, const float* Cin, void* out,
                  int outBf16, int M, int N, int K, int ldb, const float* bias, int act) {
    gemm_bf16_kernel<<<dim3(N / 64, M / 128), 256, 0, stream>>>(
        A, Bt, Cin, out, outBf16, M, N, K, ldb, bias, act);
  };

  // 1) degrees
  hipMemsetAsync(deg, 0, (size_t)12 * kNL * sizeof(float), stream);
  count_deg_kernel<<<12 * kE / 256, 256, 0, stream>>>(ep, deg);
  finalize_deg_kernel<<<12 * kNL / 256, 256, 0, stream>>>(deg);

  // 2) conversions (inputs + weights)
  cvt(h_L, hLb, (size_t)kNL * kFEAT);
  cvt(h_D, hDb, (size_t)kND * kFEAT);
  cvt(h_M, hMb, (size_t)kNM * kFEAT);
  cvt(Adj, Adjb, (size_t)kSIZE * kITEMS);
  for (int t = 0; t < 6; ++t) {
    tconv(W[0] + (size_t)t * kFEAT * kHID, W1t + (size_t)t * kFEAT * kHID, kFEAT, kHID);
    tconv(W[1] + (size_t)t * kHID * kHID,  W2t + (size_t)t * kHID * kHID,  kHID,  kHID);
    tconv(W[2] + (size_t)t * kHID * kOUTF, W3t + (size_t)t * kHID * kOUTF, kHID,  kOUTF);
  }
  tconv(f1_w, f1t, kITEMS + kOUTF, 256);
  tconv(f2_w, f2t, 256, 512);
  tconv(f3_w, f3t, 512, 1024);
  tconv(f4_w, f4t, 1024, kITEMS);

  const int srcT[6] = {0, 1, 0, 2, 1, 2};
  const int dstT[6] = {1, 0, 2, 0, 2, 1};
  const int nsrc[6] = {kNL, kND, kNL, kNM, kND, kNM};
  const int ndst[6] = {kND, kNL, kNM, kNL, kNM, kND};

  const ushort_t* curb[3] = {hLb, hDb, hMb};
  float* bufs[2][3] = {{bufL0, bufD0, bufM0}, {bufL1, bufD1, bufM1}};
  int nnode[3] = {kNL, kND, kNM};
  int F = kFEAT;

  // 3) hetero layers 1 & 2 (output width 64)
  for (int layer = 0; layer < 2; ++layer) {
    int G = kHID, gshift = 6;
    float** nxt = bufs[layer];
    const ushort_t* Wt = (layer == 0) ? W1t : W2t;
    const float* bl = Bb[layer];
    init_acc_kernel<<<(kNL * G + 255) / 256, 256, 0, stream>>>(nxt[0], bl + 1 * G, bl + 3 * G, kNL * G, G - 1);
    init_acc_kernel<<<(kND * G + 255) / 256, 256, 0, stream>>>(nxt[1], bl + 0 * G, bl + 5 * G, kND * G, G - 1);
    init_acc_kernel<<<(kNM * G + 255) / 256, 256, 0, stream>>>(nxt[2], bl + 2 * G, bl + 4 * G, kNM * G, G - 1);
    for (int t = 0; t < 6; ++t) {
      gemm(curb[srcT[t]], Wt + (size_t)t * F * G, nullptr, zb, 1,
           nsrc[t], G, F, F, nullptr, 0);
      scatter_kernel<<<(kE << gshift) / 256, 256, 0, stream>>>(
          zb, ep.p[2 * t], ep.p[2 * t + 1],
          deg + (size_t)(2 * t) * kNL, deg + (size_t)(2 * t + 1) * kNL,
          nxt[dstT[t]], gshift, ndst[t]);
    }
    // convert accumulators -> bf16 inputs for next layer
    cvt(nxt[0], aLb, (size_t)kNL * G);
    cvt(nxt[1], aDb, (size_t)kND * G);
    cvt(nxt[2], aMb, (size_t)kNM * G);
    curb[0] = aLb; curb[1] = aDb; curb[2] = aMb;
    F = G;
  }

  // 4) layer 3: only oL, only rows [0, 2048)
  {
    int G = kOUTF, gshift = 7;
    const float* bl = Bb[2];
    init_acc_kernel<<<(kSIZE * G + 255) / 256, 256, 0, stream>>>(accL3, bl + 1 * G, bl + 3 * G, kSIZE * G, G - 1);
    const int types[2] = {1, 3};  // DL, ML
    for (int ti = 0; ti < 2; ++ti) {
      int t = types[ti];
      gemm(curb[srcT[t]], W3t + (size_t)t * F * G, nullptr, zb, 1,
           nsrc[t], G, F, F, nullptr, 0);
      scatter_kernel<<<(kE << gshift) / 256, 256, 0, stream>>>(
          zb, ep.p[2 * t], ep.p[2 * t + 1],
          deg + (size_t)(2 * t) * kNL, deg + (size_t)(2 * t + 1) * kNL,
          accL3, gshift, kSIZE);
    }
  }

  // 5) L1 normalize -> fake_embedding (output 0) + bf16 copy
  float* emb  = (float*)d_out;
  float* outx = (float*)d_out + (size_t)kSIZE * kOUTF;
  l1norm_kernel<<<kSIZE, 64, 0, stream>>>(accL3, emb, embb);

  // 6) MLP (bf16 MFMA, fp32 accum)
  // x1 = relu(Adj @ f1_w[:4096] + emb @ f1_w[4096:] + f1_b)
  gemm(Adjb, f1t, nullptr, x1f, 0, kSIZE, 256, kITEMS, kITEMS + kOUTF, nullptr, 0);
  gemm(embb, f1t + kITEMS, x1f, x1b, 1, kSIZE, 256, kOUTF, kITEMS + kOUTF, f1_b, 1);
  gemm(x1b, f2t, nullptr, x2b, 1, kSIZE, 512, 256, 256, f2_b, 1);
  gemm(x2b, f3t, nullptr, x3b, 1, kSIZE, 1024, 512, 512, f3_b, 1);
  gemm(x3b, f4t, nullptr, outx, 0, kSIZE, kITEMS, 1024, 1024, f4_b, 2);
}

// Round 3
// 647.757 us; speedup vs baseline: 3.1682x; 2.1901x over previous
//
#include <hip/hip_runtime.h>

constexpr int kNL = 16384, kND = 4096, kNM = 2048;
constexpr int kE = 262144;              // 2^18
constexpr int kFEAT = 256, kHID = 64, kOUTF = 128;
constexpr int kITEMS = 4096, kSIZE = 2048;
constexpr int kHB = 16;                 // histogram chunks per index array

typedef unsigned short ushort_t;
typedef unsigned int uint_t;
typedef __attribute__((ext_vector_type(8))) short short8v;
typedef __attribute__((ext_vector_type(4))) float f32x4;

struct EdgePtrs { const int* p[12]; };
struct I6 { int v[6]; };

__device__ inline ushort_t f2bf(float f) {
  unsigned u = __builtin_bit_cast(unsigned, f);
  unsigned r = u + 0x7fffu + ((u >> 16) & 1u);
  return (ushort_t)(r >> 16);
}
__device__ inline float bf2f(ushort_t b) {
  unsigned u = ((unsigned)b) << 16;
  return __builtin_bit_cast(float, u);
}

// ---- 1) per-chunk LDS-privatized histograms (no global atomics) -----------
// grid = 12*kHB blocks; block (k=blk>>4, chunk=blk&15) histograms 16384 edges.
__global__ __launch_bounds__(256) void hist_kernel(EdgePtrs ep, uint_t* __restrict__ part) {
  __shared__ uint_t bins[16384];
  int k = blockIdx.x >> 4, chunk = blockIdx.x & (kHB - 1);
  for (int i = threadIdx.x; i < 16384; i += 256) bins[i] = 0;
  __syncthreads();
  const int* arr = ep.p[k];
  int base = chunk * (kE / kHB);
  for (int i = threadIdx.x; i < kE / kHB; i += 256)
    atomicAdd(&bins[arr[base + i]], 1u);
  __syncthreads();
  uint_t* o = part + ((size_t)blockIdx.x << 14);
  for (int i = threadIdx.x; i < 16384; i += 256) o[i] = bins[i];
}

// ---- 2) reduce partials -> counts + rsqrt(max(deg,1)) ---------------------
__global__ void reduce_finalize_kernel(const uint_t* __restrict__ part,
                                       uint_t* __restrict__ cnts,
                                       float* __restrict__ degscale) {
  int idx = blockIdx.x * 256 + threadIdx.x;   // grid = 12*16384/256
  int k = idx >> 14, bin = idx & 16383;
  uint_t s = 0;
  for (int c = 0; c < kHB; ++c) s += part[((size_t)(k * kHB + c) << 14) + bin];
  cnts[idx] = s;
  degscale[idx] = rsqrtf((float)max(s, 1u));
}

// ---- 3) exclusive scan of in-degree -> rowptr per dst type ----------------
__global__ __launch_bounds__(1024) void scan_kernel(const uint_t* __restrict__ cnts,
                                                    uint_t* __restrict__ rp_all,
                                                    I6 rpoff, I6 nd) {
  __shared__ uint_t sums[1024];
  int t = blockIdx.x;
  int n = nd.v[t];
  const uint_t* c = cnts + ((size_t)(2 * t + 1) << 14);
  uint_t* rp = rp_all + rpoff.v[t];
  int tid = threadIdx.x;
  int seg = n >> 10;
  uint_t s = 0;
  for (int j = 0; j < seg; ++j) s += c[tid * seg + j];
  sums[tid] = s;
  __syncthreads();
  for (int o = 1; o < 1024; o <<= 1) {
    uint_t v = (tid >= o) ? sums[tid - o] : 0u;
    __syncthreads();
    sums[tid] += v;
    __syncthreads();
  }
  uint_t run = sums[tid] - s;   // exclusive
  for (int j = 0; j < seg; ++j) { rp[tid * seg + j] = run; run += c[tid * seg + j]; }
  if (tid == 1023) rp[n] = run;
}

// ---- 4) per-chunk base offsets: ofs[t][c][bin] ----------------------------
__global__ void chunkofs_kernel(const uint_t* __restrict__ part,
                                const uint_t* __restrict__ rp_all,
                                I6 rpoff, I6 nd, uint_t* __restrict__ ofs) {
  int idx = blockIdx.x * 256 + threadIdx.x;   // grid = 6*16384/256
  int t = idx >> 14, bin = idx & 16383;
  if (bin >= nd.v[t]) return;
  uint_t run = (rp_all + rpoff.v[t])[bin];
  for (int c = 0; c < kHB; ++c) {
    ofs[((size_t)(t * kHB + c) << 14) + bin] = run;
    run += part[((size_t)((2 * t + 1) * kHB + c) << 14) + bin];
  }
}

// ---- 5) CSR fill with LDS cursors (no global atomics) ---------------------
__global__ __launch_bounds__(256) void fill_kernel(EdgePtrs ep,
                                                   const uint_t* __restrict__ ofs,
                                                   uint_t* __restrict__ csr_all) {
  __shared__ uint_t cursor[16384];
  int t = blockIdx.x >> 4, chunk = blockIdx.x & (kHB - 1);
  const uint_t* o = ofs + ((size_t)(t * kHB + chunk) << 14);
  for (int i = threadIdx.x; i < 16384; i += 256) cursor[i] = o[i];
  __syncthreads();
  const int* srcp = ep.p[2 * t];
  const int* dstp = ep.p[2 * t + 1];
  int base = chunk * (kE / kHB);
  uint_t* csr = csr_all + (size_t)t * kE;
  for (int i = threadIdx.x; i < kE / kHB; i += 256) {
    int e = base + i;
    int d = dstp[e];
    uint_t pos = atomicAdd(&cursor[d], 1u);
    csr[pos] = (uint_t)srcp[e];
  }
}

// ---- fp32 -> bf16 elementwise (n multiple of 4) ---------------------------
__global__ void cvt_bf16_kernel(const float* __restrict__ in,
                                ushort_t* __restrict__ out, int n4) {
  int idx = blockIdx.x * 256 + threadIdx.x;
  if (idx >= n4) return;
  float4 v = ((const float4*)in)[idx];
  ushort_t* o = out + (size_t)idx * 4;
  o[0] = f2bf(v.x); o[1] = f2bf(v.y); o[2] = f2bf(v.z); o[3] = f2bf(v.w);
}

// ---- transpose + convert: in [K][N] f32 -> out [N][K] bf16 ----------------
__global__ void transpose_bf16_kernel(const float* __restrict__ in,
                                      ushort_t* __restrict__ out, int K, int N) {
  __shared__ float t[32][33];
  int n0 = blockIdx.x * 32, k0 = blockIdx.y * 32;
  int tx = threadIdx.x & 31, ty = threadIdx.x >> 5;
#pragma unroll
  for (int i = 0; i < 32; i += 8)
    t[ty + i][tx] = in[(size_t)(k0 + ty + i) * N + n0 + tx];
  __syncthreads();
#pragma unroll
  for (int i = 0; i < 32; i += 8)
    out[(size_t)(n0 + ty + i) * K + k0 + tx] = f2bf(t[tx][ty + i]);
}

// ---- bf16 MFMA GEMM: out = act( [Cin +] rowScale.*(A @ Bt^T) + bias ) -----
__global__ __launch_bounds__(256) void gemm_bf16_kernel(
    const ushort_t* __restrict__ A, const ushort_t* __restrict__ Bt,
    const float* __restrict__ Cin, void* __restrict__ out, int outBf16,
    int M, int N, int K, int ldb,
    const float* __restrict__ rowScale, const float* __restrict__ bias, int act) {
  __shared__ ushort_t As[128 * 32];
  __shared__ ushort_t Bs[64 * 32];
  int tid = threadIdx.x;
  int wave = tid >> 6, lane = tid & 63;
  int brow = blockIdx.y * 128, bcol = blockIdx.x * 64;

  int ar0 = tid >> 2;
  int as0 = tid & 3;
  int ar1 = 64 + ar0;
  const ushort_t* gA0 = A + (size_t)(brow + ar0) * K + as0 * 8;
  const ushort_t* gA1 = A + (size_t)(brow + ar1) * K + as0 * 8;
  const ushort_t* gB  = Bt + (size_t)(bcol + ar0) * ldb + as0 * 8;
  int wA0 = ar0 * 32 + ((as0 ^ ((ar0 >> 1) & 3)) * 8);
  int wA1 = ar1 * 32 + ((as0 ^ ((ar1 >> 1) & 3)) * 8);
  int wB  = ar0 * 32 + ((as0 ^ ((ar0 >> 1) & 3)) * 8);

  int fr = lane & 15, fq = lane >> 4;

  f32x4 acc[2][4] = {};
  short8v ra0 = *(const short8v*)gA0;
  short8v ra1 = *(const short8v*)gA1;
  short8v rb  = *(const short8v*)gB;

  for (int k0 = 0; k0 < K; k0 += 32) {
    __syncthreads();
    *(short8v*)(As + wA0) = ra0;
    *(short8v*)(As + wA1) = ra1;
    *(short8v*)(Bs + wB)  = rb;
    __syncthreads();
    if (k0 + 32 < K) {
      ra0 = *(const short8v*)(gA0 + k0 + 32);
      ra1 = *(const short8v*)(gA1 + k0 + 32);
      rb  = *(const short8v*)(gB + k0 + 32);
    }
    short8v af[2], bfr[4];
#pragma unroll
    for (int mi = 0; mi < 2; ++mi) {
      int row = wave * 32 + mi * 16 + fr;
      af[mi] = *(const short8v*)(As + row * 32 + ((fq ^ ((row >> 1) & 3)) * 8));
    }
#pragma unroll
    for (int ni = 0; ni < 4; ++ni) {
      int row = ni * 16 + fr;
      bfr[ni] = *(const short8v*)(Bs + row * 32 + ((fq ^ ((row >> 1) & 3)) * 8));
    }
#pragma unroll
    for (int mi = 0; mi < 2; ++mi)
#pragma unroll
      for (int ni = 0; ni < 4; ++ni)
        acc[mi][ni] = __builtin_amdgcn_mfma_f32_16x16x32_bf16(af[mi], bfr[ni], acc[mi][ni], 0, 0, 0);
  }

#pragma unroll
  for (int mi = 0; mi < 2; ++mi)
#pragma unroll
    for (int ni = 0; ni < 4; ++ni)
#pragma unroll
      for (int r = 0; r < 4; ++r) {
        int row = brow + wave * 32 + mi * 16 + fq * 4 + r;
        int col = bcol + ni * 16 + fr;
        float v = acc[mi][ni][r];
        if (rowScale) v *= rowScale[row];
        if (Cin) v += Cin[(size_t)row * N + col];
        if (bias) v += bias[col];
        if (act == 1) v = fmaxf(v, 0.0f);
        else if (act == 2) v = 1.0f / (1.0f + expf(-v));
        if (outBf16) ((ushort_t*)out)[(size_t)row * N + col] = f2bf(v);
        else ((float*)out)[(size_t)row * N + col] = v;
      }
}

// ---- CSR gather (width 64): out[d] = bf16(sIn0*Σz0 + sIn1*Σz1 + b0 + b1) --
__global__ __launch_bounds__(256) void gather64_kernel(
    const ushort_t* __restrict__ z0, const uint_t* __restrict__ rp0, const uint_t* __restrict__ cs0,
    const float* __restrict__ sIn0,
    const ushort_t* __restrict__ z1, const uint_t* __restrict__ rp1, const uint_t* __restrict__ cs1,
    const float* __restrict__ sIn1,
    const float* __restrict__ b0, const float* __restrict__ b1,
    ushort_t* __restrict__ out) {
  int d = blockIdx.x * 4 + (threadIdx.x >> 6);
  int c = threadIdx.x & 63;
  float acc;
  {
    uint_t e = rp0[d], ee = rp0[d + 1];
    float a0 = 0, a1 = 0, a2 = 0, a3 = 0;
    for (; e + 4 <= ee; e += 4) {
      uint_t s0 = cs0[e], s1 = cs0[e + 1], s2 = cs0[e + 2], s3 = cs0[e + 3];
      a0 += bf2f(z0[s0 * 64 + c]); a1 += bf2f(z0[s1 * 64 + c]);
      a2 += bf2f(z0[s2 * 64 + c]); a3 += bf2f(z0[s3 * 64 + c]);
    }
    for (; e < ee; ++e) a0 += bf2f(z0[cs0[e] * 64 + c]);
    acc = (a0 + a1 + a2 + a3) * sIn0[d];
  }
  {
    uint_t e = rp1[d], ee = rp1[d + 1];
    float a0 = 0, a1 = 0, a2 = 0, a3 = 0;
    for (; e + 4 <= ee; e += 4) {
      uint_t s0 = cs1[e], s1 = cs1[e + 1], s2 = cs1[e + 2], s3 = cs1[e + 3];
      a0 += bf2f(z1[s0 * 64 + c]); a1 += bf2f(z1[s1 * 64 + c]);
      a2 += bf2f(z1[s2 * 64 + c]); a3 += bf2f(z1[s3 * 64 + c]);
    }
    for (; e < ee; ++e) a0 += bf2f(z1[cs1[e] * 64 + c]);
    acc += (a0 + a1 + a2 + a3) * sIn1[d];
  }
  acc += b0[c] + b1[c];
  out[(size_t)d * 64 + c] = f2bf(acc);
}

// ---- layer-3 gather (width 128, d<2048) fused with L1 normalize -----------
__global__ __launch_bounds__(256) void gather128_l1_kernel(
    const ushort_t* __restrict__ zD, const uint_t* __restrict__ rpD, const uint_t* __restrict__ csD,
    const float* __restrict__ sInD,
    const ushort_t* __restrict__ zM, const uint_t* __restrict__ rpM, const uint_t* __restrict__ csM,
    const float* __restrict__ sInM,
    const float* __restrict__ bD, const float* __restrict__ bM,
    float* __restrict__ emb, ushort_t* __restrict__ embb) {
  int d = blockIdx.x * 4 + (threadIdx.x >> 6);
  int c = threadIdx.x & 63;
  float v0 = 0, v1 = 0;
  {
    uint_t e = rpD[d], ee = rpD[d + 1];
    float a0 = 0, a1 = 0, h0 = 0, h1 = 0;
    for (; e + 2 <= ee; e += 2) {
      uint_t s0 = csD[e], s1 = csD[e + 1];
      a0 += bf2f(zD[s0 * 128 + c]);      h0 += bf2f(zD[s0 * 128 + 64 + c]);
      a1 += bf2f(zD[s1 * 128 + c]);      h1 += bf2f(zD[s1 * 128 + 64 + c]);
    }
    if (e < ee) { uint_t s = csD[e]; a0 += bf2f(zD[s * 128 + c]); h0 += bf2f(zD[s * 128 + 64 + c]); }
    v0 += (a0 + a1) * sInD[d]; v1 += (h0 + h1) * sInD[d];
  }
  {
    uint_t e = rpM[d], ee = rpM[d + 1];
    float a0 = 0, a1 = 0, h0 = 0, h1 = 0;
    for (; e + 2 <= ee; e += 2) {
      uint_t s0 = csM[e], s1 = csM[e + 1];
      a0 += bf2f(zM[s0 * 128 + c]);      h0 += bf2f(zM[s0 * 128 + 64 + c]);
      a1 += bf2f(zM[s1 * 128 + c]);      h1 += bf2f(zM[s1 * 128 + 64 + c]);
    }
    if (e < ee) { uint_t s = csM[e]; a0 += bf2f(zM[s * 128 + c]); h0 += bf2f(zM[s * 128 + 64 + c]); }
    v0 += (a0 + a1) * sInM[d]; v1 += (h0 + h1) * sInM[d];
  }
  v0 += bD[c] + bM[c];
  v1 += bD[64 + c] + bM[64 + c];
  float a = fabsf(v0) + fabsf(v1);
#pragma unroll
  for (int o = 32; o > 0; o >>= 1) a += __shfl_xor(a, o);
  float l1 = fmaxf(a, 1e-12f);
  float e0 = v0 / l1, e1 = v1 / l1;
  emb[d * kOUTF + c] = e0;
  emb[d * kOUTF + 64 + c] = e1;
  embb[d * kOUTF + c] = f2bf(e0);
  embb[d * kOUTF + 64 + c] = f2bf(e1);
}

extern "C" void kernel_launch(void* const* d_in, const int* in_sizes, int n_in,
                              void* d_out, int out_size, void* d_ws, size_t ws_size,
                              hipStream_t stream) {
  const float* h_L = (const float*)d_in[0];
  const float* h_D = (const float*)d_in[1];
  const float* h_M = (const float*)d_in[2];
  const float* Adj = (const float*)d_in[3];
  EdgePtrs ep;
  for (int i = 0; i < 12; ++i) ep.p[i] = (const int*)d_in[4 + i];
  const float* W[3]  = {(const float*)d_in[16], (const float*)d_in[18], (const float*)d_in[20]};
  const float* Bb[3] = {(const float*)d_in[17], (const float*)d_in[19], (const float*)d_in[21]};
  const float* f1_w = (const float*)d_in[22];
  const float* f1_b = (const float*)d_in[23];
  const float* f2_w = (const float*)d_in[24];
  const float* f2_b = (const float*)d_in[25];
  const float* f3_w = (const float*)d_in[26];
  const float* f3_b = (const float*)d_in[27];
  const float* f4_w = (const float*)d_in[28];
  const float* f4_b = (const float*)d_in[29];

  // ---- workspace layout ----
  float* ws = (float*)d_ws;
  size_t off = 0;
  auto allocF = [&](size_t n) { float* p = ws + off; off += (n + 3) & ~(size_t)3; return p; };
  auto allocU = [&](size_t n) { return (uint_t*)allocF(n); };
  auto allocB = [&](size_t n) { return (ushort_t*)allocF((n + 1) / 2); };

  uint_t* part   = allocU((size_t)12 * kHB * 16384);   // 12 MB (reused as zb)
  uint_t* cnts   = allocU((size_t)12 * 16384);
  float*  degscale = allocF((size_t)12 * 16384);
  uint_t* rp_all = allocU(45062 + 2);
  uint_t* ofs    = allocU((size_t)6 * kHB * 16384);
  uint_t* csr    = allocU((size_t)6 * kE);
  float* x1f   = allocF((size_t)kSIZE * 256);
  ushort_t* hLb  = allocB((size_t)kNL * kFEAT);
  ushort_t* hDb  = allocB((size_t)kND * kFEAT);
  ushort_t* hMb  = allocB((size_t)kNM * kFEAT);
  ushort_t* Adjb = allocB((size_t)kSIZE * kITEMS);
  ushort_t* aLb  = allocB((size_t)kNL * kHID);
  ushort_t* aDb  = allocB((size_t)kND * kHID);
  ushort_t* aMb  = allocB((size_t)kNM * kHID);
  ushort_t* W1t  = allocB((size_t)6 * kFEAT * kHID);
  ushort_t* W2t  = allocB((size_t)6 * kHID * kHID);
  ushort_t* W3t  = allocB((size_t)6 * kHID * kOUTF);
  ushort_t* f1t  = allocB((size_t)(kITEMS + kOUTF) * 256);
  ushort_t* f2t  = allocB((size_t)256 * 512);
  ushort_t* f3t  = allocB((size_t)512 * 1024);
  ushort_t* f4t  = allocB((size_t)1024 * kITEMS);
  ushort_t* embb = allocB((size_t)kSIZE * kOUTF);
  ushort_t* x1b  = allocB((size_t)kSIZE * 256);
  ushort_t* x2b  = allocB((size_t)kSIZE * 512);
  ushort_t* x3b  = allocB((size_t)kSIZE * 1024);
  // z buffers alias `part` (dead after fill_kernel; GEMMs into z run after fill)
  ushort_t* zb = (ushort_t*)part;

  const int srcT[6] = {0, 1, 0, 2, 1, 2};
  const int nsrc[6] = {kNL, kND, kNL, kNM, kND, kNM};
  I6 ndI; const int ndst_[6] = {kND, kNL, kNM, kNL, kNM, kND};
  for (int t = 0; t < 6; ++t) ndI.v[t] = ndst_[t];
  I6 rpo; { int r = 0; for (int t = 0; t < 6; ++t) { rpo.v[t] = r; r += ndst_[t] + 1; } }
  // z offsets (bf16 elems) for 64-wide layers
  size_t zo[6]; { size_t r = 0; for (int t = 0; t < 6; ++t) { zo[t] = r; r += (size_t)nsrc[t] * 64; } }

  auto cvt = [&](const float* in, ushort_t* out, size_t n) {
    int n4 = (int)(n / 4);
    cvt_bf16_kernel<<<(n4 + 255) / 256, 256, 0, stream>>>(in, out, n4);
  };
  auto tconv = [&](const float* in, ushort_t* out, int K, int N) {
    transpose_bf16_kernel<<<dim3(N / 32, K / 32), 256, 0, stream>>>(in, out, K, N);
  };
  auto gemm = [&](const ushort_t* A, const ushort_t* Bt, const float* Cin, void* out,
                  int outBf16, int M, int N, int K, int ldb,
                  const float* rowScale, const float* bias, int act) {
    gemm_bf16_kernel<<<dim3(N / 64, M / 128), 256, 0, stream>>>(
        A, Bt, Cin, out, outBf16, M, N, K, ldb, rowScale, bias, act);
  };

  // 1) degrees + CSR build (no global atomics anywhere)
  hist_kernel<<<12 * kHB, 256, 0, stream>>>(ep, part);
  reduce_finalize_kernel<<<12 * 16384 / 256, 256, 0, stream>>>(part, cnts, degscale);
  scan_kernel<<<6, 1024, 0, stream>>>(cnts, rp_all, rpo, ndI);
  chunkofs_kernel<<<6 * 16384 / 256, 256, 0, stream>>>(part, rp_all, rpo, ndI, ofs);
  fill_kernel<<<6 * kHB, 256, 0, stream>>>(ep, ofs, csr);

  // 2) conversions
  cvt(h_L, hLb, (size_t)kNL * kFEAT);
  cvt(h_D, hDb, (size_t)kND * kFEAT);
  cvt(h_M, hMb, (size_t)kNM * kFEAT);
  cvt(Adj, Adjb, (size_t)kSIZE * kITEMS);
  for (int t = 0; t < 6; ++t) {
    tconv(W[0] + (size_t)t * kFEAT * kHID, W1t + (size_t)t * kFEAT * kHID, kFEAT, kHID);
    tconv(W[1] + (size_t)t * kHID * kHID,  W2t + (size_t)t * kHID * kHID,  kHID,  kHID);
    tconv(W[2] + (size_t)t * kHID * kOUTF, W3t + (size_t)t * kHID * kOUTF, kHID,  kOUTF);
  }
  tconv(f1_w, f1t, kITEMS + kOUTF, 256);
  tconv(f2_w, f2t, 256, 512);
  tconv(f3_w, f3t, 512, 1024);
  tconv(f4_w, f4t, 1024, kITEMS);

  const ushort_t* curb[3] = {hLb, hDb, hMb};
  int F = kFEAT;

  // 3) hetero layers 1 & 2: z_t = sOut_t .* (x @ W_t); gather per dst type
  for (int layer = 0; layer < 2; ++layer) {
    int G = kHID;
    const ushort_t* Wt = (layer == 0) ? W1t : W2t;
    const float* bl = Bb[layer];
    for (int t = 0; t < 6; ++t)
      gemm(curb[srcT[t]], Wt + (size_t)t * F * G, nullptr, zb + zo[t], 1,
           nsrc[t], G, F, F, degscale + ((size_t)(2 * t) << 14), nullptr, 0);
    // oL <- t1 (D->L), t3 (M->L)
    gather64_kernel<<<kNL / 4, 256, 0, stream>>>(
        zb + zo[1], rp_all + rpo.v[1], csr + (size_t)1 * kE, degscale + ((size_t)3 << 14),
        zb + zo[3], rp_all + rpo.v[3], csr + (size_t)3 * kE, degscale + ((size_t)7 << 14),
        bl + 1 * G, bl + 3 * G, aLb);
    // oD <- t0 (L->D), t5 (M->D)
    gather64_kernel<<<kND / 4, 256, 0, stream>>>(
        zb + zo[0], rp_all + rpo.v[0], csr + (size_t)0 * kE, degscale + ((size_t)1 << 14),
        zb + zo[5], rp_all + rpo.v[5], csr + (size_t)5 * kE, degscale + ((size_t)11 << 14),
        bl + 0 * G, bl + 5 * G, aDb);
    // oM <- t2 (L->M), t4 (D->M)
    gather64_kernel<<<kNM / 4, 256, 0, stream>>>(
        zb + zo[2], rp_all + rpo.v[2], csr + (size_t)2 * kE, degscale + ((size_t)5 << 14),
        zb + zo[4], rp_all + rpo.v[4], csr + (size_t)4 * kE, degscale + ((size_t)9 << 14),
        bl + 2 * G, bl + 4 * G, aMb);
    curb[0] = aLb; curb[1] = aDb; curb[2] = aMb;
    F = G;
  }

  // 4) layer 3: only oL rows [0,2048): types t1 (src D), t3 (src M); fused L1 norm
  float* emb  = (float*)d_out;
  float* outx = (float*)d_out + (size_t)kSIZE * kOUTF;
  {
    int G = kOUTF;
    ushort_t* zD3 = zb;                                  // 4096 x 128
    ushort_t* zM3 = zb + (size_t)kND * kOUTF;            // 2048 x 128
    gemm(curb[1], W3t + (size_t)1 * F * G, nullptr, zD3, 1,
         kND, G, F, F, degscale + ((size_t)2 << 14), nullptr, 0);
    gemm(curb[2], W3t + (size_t)3 * F * G, nullptr, zM3, 1,
         kNM, G, F, F, degscale + ((size_t)6 << 14), nullptr, 0);
    gather128_l1_kernel<<<kSIZE / 4, 256, 0, stream>>>(
        zD3, rp_all + rpo.v[1], csr + (size_t)1 * kE, degscale + ((size_t)3 << 14),
        zM3, rp_all + rpo.v[3], csr + (size_t)3 * kE, degscale + ((size_t)7 << 14),
        Bb[2] + 1 * G, Bb[2] + 3 * G, emb, embb);
  }

  // 5) MLP (bf16 MFMA, fp32 accum)
  gemm(Adjb, f1t, nullptr, x1f, 0, kSIZE, 256, kITEMS, kITEMS + kOUTF, nullptr, nullptr, 0);
  gemm(embb, f1t + kITEMS, x1f, x1b, 1, kSIZE, 256, kOUTF, kITEMS + kOUTF, nullptr, f1_b, 1);
  gemm(x1b, f2t, nullptr, x2b, 1, kSIZE, 512, 256, 256, nullptr, f2_b, 1);
  gemm(x2b, f3t, nullptr, x3b, 1, kSIZE, 1024, 512, 512, nullptr, f3_b, 1);
  gemm(x3b, f4t, nullptr, outx, 0, kSIZE, kITEMS, 1024, 1024, nullptr, f4_b, 2);
}

// Round 4
// 417.333 us; speedup vs baseline: 4.9174x; 1.5521x over previous
//
#include <hip/hip_runtime.h>

constexpr int kNL = 16384, kND = 4096, kNM = 2048;
constexpr int kE = 262144;              // 2^18
constexpr int kFEAT = 256, kHID = 64, kOUTF = 128;
constexpr int kITEMS = 4096, kSIZE = 2048;
constexpr int kHB = 16;                 // histogram chunks per index array
constexpr int kZS = 128;                // z row stride (merged 2-type layout)

typedef unsigned short ushort_t;
typedef unsigned int uint_t;
typedef __attribute__((ext_vector_type(8))) short short8v;
typedef __attribute__((ext_vector_type(4))) float f32x4;

struct EdgePtrs { const int* p[12]; };
struct I6 { int v[6]; };

__device__ inline ushort_t f2bf(float f) {
  unsigned u = __builtin_bit_cast(unsigned, f);
  unsigned r = u + 0x7fffu + ((u >> 16) & 1u);
  return (ushort_t)(r >> 16);
}
__device__ inline float bf2f(ushort_t b) {
  unsigned u = ((unsigned)b) << 16;
  return __builtin_bit_cast(float, u);
}

// ===== prep: all fp32->bf16 converts + transpose-converts in ONE launch ====
struct PJob { const float* in; ushort_t* out; int A; int B; int kind; int nblk; };
struct PJobs { PJob j[24]; int n; };

__global__ __launch_bounds__(256) void prep_kernel(PJobs jobs) {
  __shared__ float t[32][33];
  int b = blockIdx.x;
  int ji = 0;
  while (ji < jobs.n && b >= jobs.j[ji].nblk) { b -= jobs.j[ji].nblk; ++ji; }
  if (ji >= jobs.n) return;
  PJob jb = jobs.j[ji];
  if (jb.kind == 0) {                       // flat convert, A = n4
    int idx = b * 256 + threadIdx.x;
    if (idx >= jb.A) return;
    float4 v = ((const float4*)jb.in)[idx];
    ushort_t* o = jb.out + (size_t)idx * 4;
    o[0] = f2bf(v.x); o[1] = f2bf(v.y); o[2] = f2bf(v.z); o[3] = f2bf(v.w);
  } else {                                  // transpose: in [K][N] -> out [N][K]; A=K, B=N
    int K = jb.A, N = jb.B;
    int tpr = N >> 5;
    int n0 = (b % tpr) * 32, k0 = (b / tpr) * 32;
    int tx = threadIdx.x & 31, ty = threadIdx.x >> 5;
#pragma unroll
    for (int i = 0; i < 32; i += 8)
      t[ty + i][tx] = jb.in[(size_t)(k0 + ty + i) * N + n0 + tx];
    __syncthreads();
#pragma unroll
    for (int i = 0; i < 32; i += 8)
      jb.out[(size_t)(n0 + ty + i) * K + k0 + tx] = f2bf(t[tx][ty + i]);
  }
}

// ===== degree/CSR build (no global atomics) ================================
__global__ __launch_bounds__(256) void hist_kernel(EdgePtrs ep, uint_t* __restrict__ part) {
  __shared__ uint_t bins[16384];
  int k = blockIdx.x >> 4, chunk = blockIdx.x & (kHB - 1);
  for (int i = threadIdx.x; i < 16384; i += 256) bins[i] = 0;
  __syncthreads();
  const int* arr = ep.p[k];
  int base = chunk * (kE / kHB);
  for (int i = threadIdx.x; i < kE / kHB; i += 256)
    atomicAdd(&bins[arr[base + i]], 1u);
  __syncthreads();
  uint_t* o = part + ((size_t)blockIdx.x << 14);
  for (int i = threadIdx.x; i < 16384; i += 256) o[i] = bins[i];
}

__global__ void reduce_finalize_kernel(const uint_t* __restrict__ part,
                                       uint_t* __restrict__ cnts,
                                       float* __restrict__ degscale) {
  int idx = blockIdx.x * 256 + threadIdx.x;   // grid = 12*16384/256
  int k = idx >> 14, bin = idx & 16383;
  uint_t s = 0;
  for (int c = 0; c < kHB; ++c) s += part[((size_t)(k * kHB + c) << 14) + bin];
  cnts[idx] = s;
  degscale[idx] = rsqrtf((float)max(s, 1u));
}

__global__ __launch_bounds__(1024) void scan_kernel(const uint_t* __restrict__ cnts,
                                                    uint_t* __restrict__ rp_all,
                                                    I6 rpoff, I6 nd) {
  __shared__ uint_t sums[1024];
  int t = blockIdx.x;
  int n = nd.v[t];
  const uint_t* c = cnts + ((size_t)(2 * t + 1) << 14);
  uint_t* rp = rp_all + rpoff.v[t];
  int tid = threadIdx.x;
  int seg = n >> 10;
  uint_t s = 0;
  for (int j = 0; j < seg; ++j) s += c[tid * seg + j];
  sums[tid] = s;
  __syncthreads();
  for (int o = 1; o < 1024; o <<= 1) {
    uint_t v = (tid >= o) ? sums[tid - o] : 0u;
    __syncthreads();
    sums[tid] += v;
    __syncthreads();
  }
  uint_t run = sums[tid] - s;   // exclusive
  for (int j = 0; j < seg; ++j) { rp[tid * seg + j] = run; run += c[tid * seg + j]; }
  if (tid == 1023) rp[n] = run;
}

__global__ void chunkofs_kernel(const uint_t* __restrict__ part,
                                const uint_t* __restrict__ rp_all,
                                I6 rpoff, I6 nd, uint_t* __restrict__ ofs) {
  int idx = blockIdx.x * 256 + threadIdx.x;   // grid = 6*16384/256
  int t = idx >> 14, bin = idx & 16383;
  if (bin >= nd.v[t]) return;
  uint_t run = (rp_all + rpoff.v[t])[bin];
  for (int c = 0; c < kHB; ++c) {
    ofs[((size_t)(t * kHB + c) << 14) + bin] = run;
    run += part[((size_t)((2 * t + 1) * kHB + c) << 14) + bin];
  }
}

__global__ __launch_bounds__(256) void fill_kernel(EdgePtrs ep,
                                                   const uint_t* __restrict__ ofs,
                                                   uint_t* __restrict__ csr_all) {
  __shared__ uint_t cursor[16384];
  int t = blockIdx.x >> 4, chunk = blockIdx.x & (kHB - 1);
  const uint_t* o = ofs + ((size_t)(t * kHB + chunk) << 14);
  for (int i = threadIdx.x; i < 16384; i += 256) cursor[i] = o[i];
  __syncthreads();
  const int* srcp = ep.p[2 * t];
  const int* dstp = ep.p[2 * t + 1];
  int base = chunk * (kE / kHB);
  uint_t* csr = csr_all + (size_t)t * kE;
  for (int i = threadIdx.x; i < kE / kHB; i += 256) {
    int e = base + i;
    int d = dstp[e];
    uint_t pos = atomicAdd(&cursor[d], 1u);
    csr[pos] = (uint_t)srcp[e];
  }
}

// ===== generic bf16 MFMA GEMM, 128x128 tile ================================
// out = act([Cin +] A @ Bt^T + bias); split-K mode when partOut != null.
__global__ __launch_bounds__(256) void gemm_bf16_kernel(
    const ushort_t* __restrict__ A, const ushort_t* __restrict__ Bt,
    const float* __restrict__ Cin, void* __restrict__ out, int outBf16,
    int M, int N, int K, int ldb,
    const float* __restrict__ bias, int act,
    int kChunk, float* __restrict__ partOut) {
  __shared__ ushort_t As[128 * 32];
  __shared__ ushort_t Bs[128 * 32];
  int tid = threadIdx.x;
  int wave = tid >> 6, lane = tid & 63;
  int brow = blockIdx.y * 128, bcol = blockIdx.x * 128;
  int kStart = partOut ? blockIdx.z * kChunk : 0;
  int kLen = partOut ? kChunk : K;

  int ar0 = tid >> 2;            // 0..63
  int as0 = tid & 3;             // 16B slot
  int ar1 = 64 + ar0;
  const ushort_t* gA0 = A + (size_t)(brow + ar0) * K + kStart + as0 * 8;
  const ushort_t* gA1 = A + (size_t)(brow + ar1) * K + kStart + as0 * 8;
  const ushort_t* gB0 = Bt + (size_t)(bcol + ar0) * ldb + kStart + as0 * 8;
  const ushort_t* gB1 = Bt + (size_t)(bcol + ar1) * ldb + kStart + as0 * 8;
  int wA0 = ar0 * 32 + ((as0 ^ ((ar0 >> 1) & 3)) * 8);
  int wA1 = ar1 * 32 + ((as0 ^ ((ar1 >> 1) & 3)) * 8);

  int fr = lane & 15, fq = lane >> 4;

  f32x4 acc[2][8] = {};
  short8v ra0 = *(const short8v*)gA0;
  short8v ra1 = *(const short8v*)gA1;
  short8v rb0 = *(const short8v*)gB0;
  short8v rb1 = *(const short8v*)gB1;

  for (int k0 = 0; k0 < kLen; k0 += 32) {
    __syncthreads();
    *(short8v*)(As + wA0) = ra0;
    *(short8v*)(As + wA1) = ra1;
    *(short8v*)(Bs + wA0) = rb0;
    *(short8v*)(Bs + wA1) = rb1;
    __syncthreads();
    if (k0 + 32 < kLen) {
      ra0 = *(const short8v*)(gA0 + k0 + 32);
      ra1 = *(const short8v*)(gA1 + k0 + 32);
      rb0 = *(const short8v*)(gB0 + k0 + 32);
      rb1 = *(const short8v*)(gB1 + k0 + 32);
    }
    short8v af[2], bfr[8];
#pragma unroll
    for (int mi = 0; mi < 2; ++mi) {
      int row = wave * 32 + mi * 16 + fr;
      af[mi] = *(const short8v*)(As + row * 32 + ((fq ^ ((row >> 1) & 3)) * 8));
    }
#pragma unroll
    for (int ni = 0; ni < 8; ++ni) {
      int row = ni * 16 + fr;
      bfr[ni] = *(const short8v*)(Bs + row * 32 + ((fq ^ ((row >> 1) & 3)) * 8));
    }
#pragma unroll
    for (int mi = 0; mi < 2; ++mi)
#pragma unroll
      for (int ni = 0; ni < 8; ++ni)
        acc[mi][ni] = __builtin_amdgcn_mfma_f32_16x16x32_bf16(af[mi], bfr[ni], acc[mi][ni], 0, 0, 0);
  }

  if (partOut) {
    float* o = partOut + (size_t)blockIdx.z * M * N;
#pragma unroll
    for (int mi = 0; mi < 2; ++mi)
#pragma unroll
      for (int ni = 0; ni < 8; ++ni)
#pragma unroll
        for (int r = 0; r < 4; ++r) {
          int row = brow + wave * 32 + mi * 16 + fq * 4 + r;
          int col = bcol + ni * 16 + fr;
          o[(size_t)row * N + col] = acc[mi][ni][r];
        }
    return;
  }
#pragma unroll
  for (int mi = 0; mi < 2; ++mi)
#pragma unroll
    for (int ni = 0; ni < 8; ++ni)
#pragma unroll
      for (int r = 0; r < 4; ++r) {
        int row = brow + wave * 32 + mi * 16 + fq * 4 + r;
        int col = bcol + ni * 16 + fr;
        float v = acc[mi][ni][r];
        if (Cin) v += Cin[(size_t)row * N + col];
        if (bias) v += bias[col];
        if (act == 1) v = fmaxf(v, 0.0f);
        else if (act == 2) v = 1.0f / (1.0f + expf(-v));
        if (outBf16) ((ushort_t*)out)[(size_t)row * N + col] = f2bf(v);
        else ((float*)out)[(size_t)row * N + col] = v;
      }
}

// ===== batched z GEMM: N=128, out = [rs0|rs1] .* (A @ Bt^T), bf16 ==========
struct ZDesc { const ushort_t* A; const ushort_t* Bt; ushort_t* out;
               const float* rs0; const float* rs1; int M; int K; };
struct ZDescs { ZDesc d[3]; };

__global__ __launch_bounds__(256) void zgemm_batched_kernel(ZDescs ds) {
  __shared__ ushort_t As[128 * 32];
  __shared__ ushort_t Bs[128 * 32];
  ZDesc de = ds.d[blockIdx.z];
  int brow = blockIdx.y * 128;
  if (brow >= de.M) return;
  int K = de.K;
  int tid = threadIdx.x;
  int wave = tid >> 6, lane = tid & 63;

  int ar0 = tid >> 2, as0 = tid & 3, ar1 = 64 + ar0;
  const ushort_t* gA0 = de.A + (size_t)(brow + ar0) * K + as0 * 8;
  const ushort_t* gA1 = de.A + (size_t)(brow + ar1) * K + as0 * 8;
  const ushort_t* gB0 = de.Bt + (size_t)ar0 * K + as0 * 8;
  const ushort_t* gB1 = de.Bt + (size_t)ar1 * K + as0 * 8;
  int wA0 = ar0 * 32 + ((as0 ^ ((ar0 >> 1) & 3)) * 8);
  int wA1 = ar1 * 32 + ((as0 ^ ((ar1 >> 1) & 3)) * 8);

  int fr = lane & 15, fq = lane >> 4;
  f32x4 acc[2][8] = {};
  short8v ra0 = *(const short8v*)gA0;
  short8v ra1 = *(const short8v*)gA1;
  short8v rb0 = *(const short8v*)gB0;
  short8v rb1 = *(const short8v*)gB1;

  for (int k0 = 0; k0 < K; k0 += 32) {
    __syncthreads();
    *(short8v*)(As + wA0) = ra0;
    *(short8v*)(As + wA1) = ra1;
    *(short8v*)(Bs + wA0) = rb0;
    *(short8v*)(Bs + wA1) = rb1;
    __syncthreads();
    if (k0 + 32 < K) {
      ra0 = *(const short8v*)(gA0 + k0 + 32);
      ra1 = *(const short8v*)(gA1 + k0 + 32);
      rb0 = *(const short8v*)(gB0 + k0 + 32);
      rb1 = *(const short8v*)(gB1 + k0 + 32);
    }
    short8v af[2], bfr[8];
#pragma unroll
    for (int mi = 0; mi < 2; ++mi) {
      int row = wave * 32 + mi * 16 + fr;
      af[mi] = *(const short8v*)(As + row * 32 + ((fq ^ ((row >> 1) & 3)) * 8));
    }
#pragma unroll
    for (int ni = 0; ni < 8; ++ni) {
      int row = ni * 16 + fr;
      bfr[ni] = *(const short8v*)(Bs + row * 32 + ((fq ^ ((row >> 1) & 3)) * 8));
    }
#pragma unroll
    for (int mi = 0; mi < 2; ++mi)
#pragma unroll
      for (int ni = 0; ni < 8; ++ni)
        acc[mi][ni] = __builtin_amdgcn_mfma_f32_16x16x32_bf16(af[mi], bfr[ni], acc[mi][ni], 0, 0, 0);
  }

#pragma unroll
  for (int mi = 0; mi < 2; ++mi)
#pragma unroll
    for (int ni = 0; ni < 8; ++ni) {
      const float* rs = (ni < 4) ? de.rs0 : de.rs1;
#pragma unroll
      for (int r = 0; r < 4; ++r) {
        int row = brow + wave * 32 + mi * 16 + fq * 4 + r;
        int col = ni * 16 + fr;
        de.out[(size_t)row * 128 + col] = f2bf(acc[mi][ni][r] * rs[row]);
      }
    }
}

// ===== batched CSR gather (width 64, z row stride 128) =====================
struct GDesc { const ushort_t* z0; const uint_t* rp0; const uint_t* cs0; const float* s0;
               const ushort_t* z1; const uint_t* rp1; const uint_t* cs1; const float* s1;
               const float* b0; const float* b1; ushort_t* out; int nd; };
struct GDescs { GDesc d[3]; };

__global__ __launch_bounds__(256) void gather_batched_kernel(GDescs ds) {
  GDesc de = ds.d[blockIdx.z];
  int d = blockIdx.x * 4 + (threadIdx.x >> 6);
  if (d >= de.nd) return;
  int c = threadIdx.x & 63;
  float acc;
  {
    uint_t e = de.rp0[d], ee = de.rp0[d + 1];
    float a0 = 0, a1 = 0, a2 = 0, a3 = 0;
    for (; e + 4 <= ee; e += 4) {
      uint_t s0 = de.cs0[e], s1 = de.cs0[e + 1], s2 = de.cs0[e + 2], s3 = de.cs0[e + 3];
      a0 += bf2f(de.z0[s0 * kZS + c]); a1 += bf2f(de.z0[s1 * kZS + c]);
      a2 += bf2f(de.z0[s2 * kZS + c]); a3 += bf2f(de.z0[s3 * kZS + c]);
    }
    for (; e < ee; ++e) a0 += bf2f(de.z0[de.cs0[e] * kZS + c]);
    acc = (a0 + a1 + a2 + a3) * de.s0[d];
  }
  {
    uint_t e = de.rp1[d], ee = de.rp1[d + 1];
    float a0 = 0, a1 = 0, a2 = 0, a3 = 0;
    for (; e + 4 <= ee; e += 4) {
      uint_t s0 = de.cs1[e], s1 = de.cs1[e + 1], s2 = de.cs1[e + 2], s3 = de.cs1[e + 3];
      a0 += bf2f(de.z1[s0 * kZS + c]); a1 += bf2f(de.z1[s1 * kZS + c]);
      a2 += bf2f(de.z1[s2 * kZS + c]); a3 += bf2f(de.z1[s3 * kZS + c]);
    }
    for (; e < ee; ++e) a0 += bf2f(de.z1[de.cs1[e] * kZS + c]);
    acc += (a0 + a1 + a2 + a3) * de.s1[d];
  }
  acc += de.b0[c] + de.b1[c];
  de.out[(size_t)d * 64 + c] = f2bf(acc);
}

// ===== layer-3 gather (width 128, d<2048) fused with L1 normalize ==========
__global__ __launch_bounds__(256) void gather128_l1_kernel(
    const ushort_t* __restrict__ zD, const uint_t* __restrict__ rpD, const uint_t* __restrict__ csD,
    const float* __restrict__ sInD,
    const ushort_t* __restrict__ zM, const uint_t* __restrict__ rpM, const uint_t* __restrict__ csM,
    const float* __restrict__ sInM,
    const float* __restrict__ bD, const float* __restrict__ bM,
    float* __restrict__ emb, ushort_t* __restrict__ embb) {
  int d = blockIdx.x * 4 + (threadIdx.x >> 6);
  int c = threadIdx.x & 63;
  float v0 = 0, v1 = 0;
  {
    uint_t e = rpD[d], ee = rpD[d + 1];
    float a0 = 0, a1 = 0, h0 = 0, h1 = 0;
    for (; e + 2 <= ee; e += 2) {
      uint_t s0 = csD[e], s1 = csD[e + 1];
      a0 += bf2f(zD[s0 * 128 + c]);      h0 += bf2f(zD[s0 * 128 + 64 + c]);
      a1 += bf2f(zD[s1 * 128 + c]);      h1 += bf2f(zD[s1 * 128 + 64 + c]);
    }
    if (e < ee) { uint_t s = csD[e]; a0 += bf2f(zD[s * 128 + c]); h0 += bf2f(zD[s * 128 + 64 + c]); }
    v0 += (a0 + a1) * sInD[d]; v1 += (h0 + h1) * sInD[d];
  }
  {
    uint_t e = rpM[d], ee = rpM[d + 1];
    float a0 = 0, a1 = 0, h0 = 0, h1 = 0;
    for (; e + 2 <= ee; e += 2) {
      uint_t s0 = csM[e], s1 = csM[e + 1];
      a0 += bf2f(zM[s0 * 128 + c]);      h0 += bf2f(zM[s0 * 128 + 64 + c]);
      a1 += bf2f(zM[s1 * 128 + c]);      h1 += bf2f(zM[s1 * 128 + 64 + c]);
    }
    if (e < ee) { uint_t s = csM[e]; a0 += bf2f(zM[s * 128 + c]); h0 += bf2f(zM[s * 128 + 64 + c]); }
    v0 += (a0 + a1) * sInM[d]; v1 += (h0 + h1) * sInM[d];
  }
  v0 += bD[c] + bM[c];
  v1 += bD[64 + c] + bM[64 + c];
  float a = fabsf(v0) + fabsf(v1);
#pragma unroll
  for (int o = 32; o > 0; o >>= 1) a += __shfl_xor(a, o);
  float l1 = fmaxf(a, 1e-12f);
  float e0 = v0 / l1, e1 = v1 / l1;
  emb[d * kOUTF + c] = e0;
  emb[d * kOUTF + 64 + c] = e1;
  embb[d * kOUTF + c] = f2bf(e0);
  embb[d * kOUTF + 64 + c] = f2bf(e1);
}

// ===== split-K reduce ======================================================
__global__ void reducek_kernel(const float* __restrict__ P, float* __restrict__ out,
                               int n4, int S) {
  int idx = blockIdx.x * 256 + threadIdx.x;
  if (idx >= n4) return;
  float4 a = ((const float4*)P)[idx];
  for (int s = 1; s < S; ++s) {
    float4 b = ((const float4*)P)[(size_t)s * n4 + idx];
    a.x += b.x; a.y += b.y; a.z += b.z; a.w += b.w;
  }
  ((float4*)out)[idx] = a;
}

extern "C" void kernel_launch(void* const* d_in, const int* in_sizes, int n_in,
                              void* d_out, int out_size, void* d_ws, size_t ws_size,
                              hipStream_t stream) {
  const float* h_L = (const float*)d_in[0];
  const float* h_D = (const float*)d_in[1];
  const float* h_M = (const float*)d_in[2];
  const float* Adj = (const float*)d_in[3];
  EdgePtrs ep;
  for (int i = 0; i < 12; ++i) ep.p[i] = (const int*)d_in[4 + i];
  const float* W[3]  = {(const float*)d_in[16], (const float*)d_in[18], (const float*)d_in[20]};
  const float* Bb[3] = {(const float*)d_in[17], (const float*)d_in[19], (const float*)d_in[21]};
  const float* f1_w = (const float*)d_in[22];
  const float* f1_b = (const float*)d_in[23];
  const float* f2_w = (const float*)d_in[24];
  const float* f2_b = (const float*)d_in[25];
  const float* f3_w = (const float*)d_in[26];
  const float* f3_b = (const float*)d_in[27];
  const float* f4_w = (const float*)d_in[28];
  const float* f4_b = (const float*)d_in[29];

  // ---- workspace layout ----
  float* ws = (float*)d_ws;
  size_t off = 0;
  auto allocF = [&](size_t n) { float* p = ws + off; off += (n + 3) & ~(size_t)3; return p; };
  auto allocU = [&](size_t n) { return (uint_t*)allocF(n); };
  auto allocB = [&](size_t n) { return (ushort_t*)allocF((n + 1) / 2); };

  uint_t* part   = allocU((size_t)12 * kHB * 16384);   // 12.6 MB, reused as z bufs
  uint_t* cnts   = allocU((size_t)12 * 16384);
  float*  degscale = allocF((size_t)12 * 16384);
  uint_t* rp_all = allocU(45062 + 2);
  uint_t* ofs    = allocU((size_t)6 * kHB * 16384);
  uint_t* csr    = allocU((size_t)6 * kE);
  float* x1f   = allocF((size_t)kSIZE * 256);
  ushort_t* hLb  = allocB((size_t)kNL * kFEAT);
  ushort_t* hDb  = allocB((size_t)kND * kFEAT);
  ushort_t* hMb  = allocB((size_t)kNM * kFEAT);
  ushort_t* Adjb = allocB((size_t)kSIZE * kITEMS);
  ushort_t* aLb  = allocB((size_t)kNL * kHID);
  ushort_t* aDb  = allocB((size_t)kND * kHID);
  ushort_t* aMb  = allocB((size_t)kNM * kHID);
  ushort_t* WLt  = allocB((size_t)128 * kFEAT);   // layer1 [W0;W2]^T
  ushort_t* WDt  = allocB((size_t)128 * kFEAT);   // [W1;W4]^T
  ushort_t* WMt  = allocB((size_t)128 * kFEAT);   // [W3;W5]^T
  ushort_t* WL2t = allocB((size_t)128 * kHID);
  ushort_t* WD2t = allocB((size_t)128 * kHID);
  ushort_t* WM2t = allocB((size_t)128 * kHID);
  ushort_t* W3t1 = allocB((size_t)kOUTF * kHID);
  ushort_t* W3t3 = allocB((size_t)kOUTF * kHID);
  ushort_t* f1t  = allocB((size_t)256 * (kITEMS + kOUTF));
  ushort_t* f2t  = allocB((size_t)512 * 256);
  ushort_t* f3t  = allocB((size_t)1024 * 512);
  ushort_t* f4t  = allocB((size_t)kITEMS * 1024);
  ushort_t* embb = allocB((size_t)kSIZE * kOUTF);
  ushort_t* x1b  = allocB((size_t)kSIZE * 256);
  ushort_t* x2b  = allocB((size_t)kSIZE * 512);
  ushort_t* x3b  = allocB((size_t)kSIZE * 1024);

  // split-K partials if workspace allows
  int S = 1;
  float* partK = x1f;
  if ((off + (size_t)8 * kSIZE * 256 + 16) * 4 <= ws_size) {
    S = 8;
    partK = allocF((size_t)8 * kSIZE * 256);
  }

  // z buffers alias `part` (dead after chunkofs/fill)
  ushort_t* zL  = (ushort_t*)part;                       // 16384 x 128
  ushort_t* zD  = zL + (size_t)kNL * kZS;                // 4096 x 128
  ushort_t* zM  = zD + (size_t)kND * kZS;                // 2048 x 128
  ushort_t* zD3 = zM + (size_t)kNM * kZS;                // 4096 x 128
  ushort_t* zM3 = zD3 + (size_t)kND * kZS;               // 2048 x 128

  I6 ndI; const int ndst_[6] = {kND, kNL, kNM, kNL, kNM, kND};
  for (int t = 0; t < 6; ++t) ndI.v[t] = ndst_[t];
  I6 rpo; { int r = 0; for (int t = 0; t < 6; ++t) { rpo.v[t] = r; r += ndst_[t] + 1; } }
  auto dsc = [&](int k) { return degscale + ((size_t)k << 14); };

  // ---- 1) one prep launch: converts + all weight transposes ----
  PJobs pj; int nj = 0; int totblk = 0;
  auto addCvt = [&](const float* in, ushort_t* out, size_t n) {
    int n4 = (int)(n / 4);
    pj.j[nj] = {in, out, n4, 0, 0, (n4 + 255) / 256}; totblk += pj.j[nj].nblk; ++nj;
  };
  auto addT = [&](const float* in, ushort_t* out, int K, int N) {
    pj.j[nj] = {in, out, K, N, 1, (N / 32) * (K / 32)}; totblk += pj.j[nj].nblk; ++nj;
  };
  addCvt(h_L, hLb, (size_t)kNL * kFEAT);
  addCvt(h_D, hDb, (size_t)kND * kFEAT);
  addCvt(h_M, hMb, (size_t)kNM * kFEAT);
  addCvt(Adj, Adjb, (size_t)kSIZE * kITEMS);
  // layer1 merged weights (K=256, each slice 64 rows)
  addT(W[0] + (size_t)0 * kFEAT * kHID, WLt + (size_t)0 * kFEAT, kFEAT, kHID);
  addT(W[0] + (size_t)2 * kFEAT * kHID, WLt + (size_t)64 * kFEAT, kFEAT, kHID);
  addT(W[0] + (size_t)1 * kFEAT * kHID, WDt + (size_t)0 * kFEAT, kFEAT, kHID);
  addT(W[0] + (size_t)4 * kFEAT * kHID, WDt + (size_t)64 * kFEAT, kFEAT, kHID);
  addT(W[0] + (size_t)3 * kFEAT * kHID, WMt + (size_t)0 * kFEAT, kFEAT, kHID);
  addT(W[0] + (size_t)5 * kFEAT * kHID, WMt + (size_t)64 * kFEAT, kFEAT, kHID);
  // layer2 merged weights (K=64)
  addT(W[1] + (size_t)0 * kHID * kHID, WL2t + (size_t)0 * kHID, kHID, kHID);
  addT(W[1] + (size_t)2 * kHID * kHID, WL2t + (size_t)64 * kHID, kHID, kHID);
  addT(W[1] + (size_t)1 * kHID * kHID, WD2t + (size_t)0 * kHID, kHID, kHID);
  addT(W[1] + (size_t)4 * kHID * kHID, WD2t + (size_t)64 * kHID, kHID, kHID);
  addT(W[1] + (size_t)3 * kHID * kHID, WM2t + (size_t)0 * kHID, kHID, kHID);
  addT(W[1] + (size_t)5 * kHID * kHID, WM2t + (size_t)64 * kHID, kHID, kHID);
  // layer3: only types 1, 3 (N=128)
  addT(W[2] + (size_t)1 * kHID * kOUTF, W3t1, kHID, kOUTF);
  addT(W[2] + (size_t)3 * kHID * kOUTF, W3t3, kHID, kOUTF);
  // MLP weights
  addT(f1_w, f1t, kITEMS + kOUTF, 256);
  addT(f2_w, f2t, 256, 512);
  addT(f3_w, f3t, 512, 1024);
  addT(f4_w, f4t, 1024, kITEMS);
  pj.n = nj;
  prep_kernel<<<totblk, 256, 0, stream>>>(pj);

  // ---- 2) degree + CSR build ----
  hist_kernel<<<12 * kHB, 256, 0, stream>>>(ep, part);
  reduce_finalize_kernel<<<12 * 16384 / 256, 256, 0, stream>>>(part, cnts, degscale);
  scan_kernel<<<6, 1024, 0, stream>>>(cnts, rp_all, rpo, ndI);
  chunkofs_kernel<<<6 * 16384 / 256, 256, 0, stream>>>(part, rp_all, rpo, ndI, ofs);
  fill_kernel<<<6 * kHB, 256, 0, stream>>>(ep, ofs, csr);

  // ---- 3) Adj @ f1_w[:4096] with split-K ----
  gemm_bf16_kernel<<<dim3(2, 16, S), 256, 0, stream>>>(
      Adjb, f1t, nullptr, nullptr, 0, kSIZE, 256, kITEMS, kITEMS + kOUTF,
      nullptr, 0, kITEMS / S, partK);
  if (S > 1)
    reducek_kernel<<<kSIZE * 256 / 4 / 256, 256, 0, stream>>>(partK, x1f, kSIZE * 256 / 4, S);

  // ---- 4) GNN layers 1 & 2 ----
  const ushort_t* curb[3] = {hLb, hDb, hMb};
  for (int layer = 0; layer < 2; ++layer) {
    int K = (layer == 0) ? kFEAT : kHID;
    const ushort_t* WtL = (layer == 0) ? WLt : WL2t;
    const ushort_t* WtD = (layer == 0) ? WDt : WD2t;
    const ushort_t* WtM = (layer == 0) ? WMt : WM2t;
    const float* bl = Bb[layer];
    ZDescs zd;
    zd.d[0] = {curb[0], WtL, zL, dsc(0), dsc(4),  kNL, K};
    zd.d[1] = {curb[1], WtD, zD, dsc(2), dsc(8),  kND, K};
    zd.d[2] = {curb[2], WtM, zM, dsc(6), dsc(10), kNM, K};
    zgemm_batched_kernel<<<dim3(1, kNL / 128, 3), 256, 0, stream>>>(zd);
    GDescs gd;
    // oL <- t1 (zD cols 0-63) + t3 (zM cols 0-63)
    gd.d[0] = {zD, rp_all + rpo.v[1], csr + (size_t)1 * kE, dsc(3),
               zM, rp_all + rpo.v[3], csr + (size_t)3 * kE, dsc(7),
               bl + 1 * kHID, bl + 3 * kHID, aLb, kNL};
    // oD <- t0 (zL cols 0-63) + t5 (zM cols 64-127)
    gd.d[1] = {zL, rp_all + rpo.v[0], csr + (size_t)0 * kE, dsc(1),
               zM + 64, rp_all + rpo.v[5], csr + (size_t)5 * kE, dsc(11),
               bl + 0 * kHID, bl + 5 * kHID, aDb, kND};
    // oM <- t2 (zL cols 64-127) + t4 (zD cols 64-127)
    gd.d[2] = {zL + 64, rp_all + rpo.v[2], csr + (size_t)2 * kE, dsc(5),
               zD + 64, rp_all + rpo.v[4], csr + (size_t)4 * kE, dsc(9),
               bl + 2 * kHID, bl + 4 * kHID, aMb, kNM};
    gather_batched_kernel<<<dim3(kNL / 4, 1, 3), 256, 0, stream>>>(gd);
    curb[0] = aLb; curb[1] = aDb; curb[2] = aMb;
  }

  // ---- 5) layer 3 (types 1: D->L, 3: M->L; rows < 2048) + L1 norm ----
  float* emb  = (float*)d_out;
  float* outx = (float*)d_out + (size_t)kSIZE * kOUTF;
  {
    ZDescs zd;
    zd.d[0] = {curb[1], W3t1, zD3, dsc(2), dsc(2), kND, kHID};
    zd.d[1] = {curb[2], W3t3, zM3, dsc(6), dsc(6), kNM, kHID};
    zd.d[2] = zd.d[1];
    zgemm_batched_kernel<<<dim3(1, kND / 128, 2), 256, 0, stream>>>(zd);
    gather128_l1_kernel<<<kSIZE / 4, 256, 0, stream>>>(
        zD3, rp_all + rpo.v[1], csr + (size_t)1 * kE, dsc(3),
        zM3, rp_all + rpo.v[3], csr + (size_t)3 * kE, dsc(7),
        Bb[2] + 1 * kOUTF, Bb[2] + 3 * kOUTF, emb, embb);
  }

  // ---- 6) MLP ----
  gemm_bf16_kernel<<<dim3(2, 16, 1), 256, 0, stream>>>(
      embb, f1t + kITEMS, x1f, x1b, 1, kSIZE, 256, kOUTF, kITEMS + kOUTF,
      f1_b, 1, 0, nullptr);
  gemm_bf16_kernel<<<dim3(4, 16, 1), 256, 0, stream>>>(
      x1b, f2t, nullptr, x2b, 1, kSIZE, 512, 256, 256, f2_b, 1, 0, nullptr);
  gemm_bf16_kernel<<<dim3(8, 16, 1), 256, 0, stream>>>(
      x2b, f3t, nullptr, x3b, 1, kSIZE, 1024, 512, 512, f3_b, 1, 0, nullptr);
  gemm_bf16_kernel<<<dim3(32, 16, 1), 256, 0, stream>>>(
      x3b, f4t, nullptr, outx, 0, kSIZE, kITEMS, 1024, 1024, f4_b, 2, 0, nullptr);
}